// Round 6
// baseline (276.606 us; speedup 1.0000x reference)
//
#include <hip/hip_runtime.h>
#include <hip/hip_bf16.h>
#include <math.h>

// Problem constants
#define BQ 4
#define NQ 100
#define MQ 50
#define HWSZ 65536
#define NP 112   // padded N rows in partials (7 x 16)
#define MP 64    // padded M (4 x 16)
#define DCLAMP 13.8155106f   // logit(1-1e-6) = -logit(1e-6)
#define ONESBF2 0x3F803F80u  // two bf16 1.0s

typedef __attribute__((ext_vector_type(8))) short short8;
typedef __attribute__((ext_vector_type(4))) float f32x4;

// d = log(pm)-log(1-pm) = clamp(x, +-13.8155) EXACTLY (logit o clip o sigmoid).
// pm = sigmoid(clamp(x)); l1m = log(1-pm) = -log(1+e^xc).
__device__ __forceinline__ void xform2(float x, float& d, float& pm, float& l1m) {
    float xc = fminf(fmaxf(x, -DCLAMP), DCLAMP);
    d = xc;
    float e = __expf(xc);                       // in [1e-6, 1e6], no overflow
    float r = __builtin_amdgcn_rcpf(1.0f + e);
    pm = e * r;
    l1m = -__logf(1.0f + e);
}

// pack two floats -> two bf16 (RTNE) in one u32
__device__ __forceinline__ unsigned pk2(float a, float b) {
    __hip_bfloat162 h = __float22bfloat162_rn(float2{a, b});
    unsigned u;
    __builtin_memcpy(&u, &h, 4);
    return u;
}

// build a bf16x8 MFMA fragment from two float4
__device__ __forceinline__ short8 mk8(float4 a, float4 b) {
    union { short8 s; unsigned u[4]; } r;
    r.u[0] = pk2(a.x, a.y); r.u[1] = pk2(a.z, a.w);
    r.u[2] = pk2(b.x, b.y); r.u[3] = pk2(b.z, b.w);
    return r.s;
}

// build a bf16x8 MFMA fragment from 8 scalars
__device__ __forceinline__ short8 mk8s(float a0, float a1, float a2, float a3,
                                       float a4, float a5, float a6, float a7) {
    union { short8 s; unsigned u[4]; } r;
    r.u[0] = pk2(a0, a1); r.u[1] = pk2(a2, a3);
    r.u[2] = pk2(a4, a5); r.u[3] = pk2(a6, a7);
    return r.s;
}

// Load one k-slab (32 floats deep) into the (single) register stage.
__device__ __forceinline__ void load_stage(
    float4& a0, float4& a1, float4 (&bv)[4][2],
    const float* ap, const float* const (&bp)[4], int k)
{
    a0 = *(const float4*)(ap + k);
    a1 = *(const float4*)(ap + k + 4);
    #pragma unroll
    for (int mt = 0; mt < 4; mt++) {
        bv[mt][0] = *(const float4*)(bp[mt] + k);
        bv[mt][1] = *(const float4*)(bp[mt] + k + 4);
    }
}

// Pack phase: consume the stage registers entirely (transform A -> fd/fp,
// pack B -> fb[4], accumulate rsl). After this the stage regs are DEAD and
// are immediately reloaded for the next iteration.
// ONES_ROW (ntile==6): lanes with r16>=4 (global rows 100-111, padding) feed
// an all-ones A-d fragment -> acc1 rows 100-111 = colsum(tm) = St (exact).
// Ones-col (all waves): B col 50 (mt=3 padding col) feeds an all-ones
// fragment -> acc2 col 50 = rowsum(pm) = Sp.
template <bool ONES_ROW>
__device__ __forceinline__ void pack_stage(
    const float4& a0, const float4& a1, const float4 (&bv)[4][2],
    short8& fd, short8& fp, short8 (&fb)[4], float& rsl,
    bool c50, bool rge4)
{
    float d0,d1,d2,d3,d4,d5,d6,d7, p0,p1,p2,p3,p4,p5,p6,p7, l;
    xform2(a0.x, d0, p0, l); rsl += l;
    xform2(a0.y, d1, p1, l); rsl += l;
    xform2(a0.z, d2, p2, l); rsl += l;
    xform2(a0.w, d3, p3, l); rsl += l;
    xform2(a1.x, d4, p4, l); rsl += l;
    xform2(a1.y, d5, p5, l); rsl += l;
    xform2(a1.z, d6, p6, l); rsl += l;
    xform2(a1.w, d7, p7, l); rsl += l;
    fd = mk8s(d0,d1,d2,d3,d4,d5,d6,d7);
    fp = mk8s(p0,p1,p2,p3,p4,p5,p6,p7);

    if (ONES_ROW) {
        union { short8 s; unsigned u[4]; } f; f.s = fd;
        f.u[0] = rge4 ? ONESBF2 : f.u[0];
        f.u[1] = rge4 ? ONESBF2 : f.u[1];
        f.u[2] = rge4 ? ONESBF2 : f.u[2];
        f.u[3] = rge4 ? ONESBF2 : f.u[3];
        fd = f.s;
    }

    #pragma unroll
    for (int mt = 0; mt < 4; mt++) {
        union { short8 s; unsigned u[4]; } f;
        f.s = mk8(bv[mt][0], bv[mt][1]);
        if (mt == 3) {
            f.u[0] = c50 ? ONESBF2 : f.u[0];
            f.u[1] = c50 ? ONESBF2 : f.u[1];
            f.u[2] = c50 ? ONESBF2 : f.u[2];
            f.u[3] = c50 ? ONESBF2 : f.u[3];
        }
        fb[mt] = f.s;
    }
}

__device__ __forceinline__ void mfma_stage(
    const short8 fd, const short8 fp, const short8 (&fb)[4],
    f32x4 (&acc1)[4], f32x4 (&acc2)[4])
{
    #pragma unroll
    for (int mt = 0; mt < 4; mt++) {
        acc1[mt] = __builtin_amdgcn_mfma_f32_16x16x32_bf16(fd, fb[mt], acc1[mt], 0, 0, 0);
        acc2[mt] = __builtin_amdgcn_mfma_f32_16x16x32_bf16(fp, fb[mt], acc2[mt], 0, 0, 0);
    }
}

template <bool ONES_ROW>
__device__ __forceinline__ void run_wave(
    const float* __restrict__ pred_masks, const float* __restrict__ tgt_masks,
    float* __restrict__ part1, float* __restrict__ part2,
    float* __restrict__ rspart,
    int nch, int Kc, int chunk, int b, int ntile)
{
    const int lane = threadIdx.x;        // 1-wave blocks
    const int r16  = lane & 15;
    const int kq8  = (lane >> 4) * 8;
    const long kbase = (long)chunk * Kc;
    const bool c50  = (r16 == 2);        // B col 48+2 = 50 (mt=3 ones-col)
    const bool rge4 = (r16 >= 4);        // A rows 100-111 (ntile=6 ones-rows)

    // A pointer: operand-layout direct load (row-clamped; rows 100-111 are
    // padding -> repurposed by ONES_ROW, never read as data)
    const int arow = min(ntile * 16 + r16, NQ - 1);
    const float* ap = pred_masks + (((long)(b * NQ + arow)) << 16) + kbase + kq8;

    // B pointers, one per m-tile (mt=3 rows 50..63 clamp to 49; col 50 is
    // repurposed as the ones-col, 51..63 never read)
    const float* bp[4];
    #pragma unroll
    for (int mt = 0; mt < 4; mt++) {
        const int brow = min(mt * 16 + r16, MQ - 1);
        bp[mt] = tgt_masks + (((long)(b * MQ + brow)) << 16) + kbase + kq8;
    }

    f32x4 acc1[4], acc2[4];
    #pragma unroll
    for (int mt = 0; mt < 4; mt++) {
        acc1[mt] = (f32x4){0.f, 0.f, 0.f, 0.f};
        acc2[mt] = (f32x4){0.f, 0.f, 0.f, 0.f};
    }
    float rsl = 0.f;

    // 1-deep pipeline in ONE stage register set (~40 VGPR): per iter,
    // pack consumes the stage (regs die) -> reload same regs for s+1 ->
    // sched_barrier(0) pins the loads BEFORE the MFMAs (round-5 lesson:
    // data deps alone let the scheduler sink loads to their uses,
    // re-serializing latency; VGPR_Count=100 was the smoking gun) ->
    // MFMAs + next iter's pack cover the load latency. TLP on top:
    // waves_per_eu(4,4) -> ~3.5 resident waves/EU x ~400 cy/iter of
    // other-wave work per stall >> 600-900 cy round trip.
    float4 A0, A1, B[4][2];
    const int nsteps = Kc / 32;          // 16 at nch=128
    load_stage(A0, A1, B, ap, bp, 0);

    for (int s = 0; s < nsteps; ++s) {
        short8 fd, fp, fb[4];
        pack_stage<ONES_ROW>(A0, A1, B, fd, fp, fb, rsl, c50, rge4);
        if (s + 1 < nsteps) {
            load_stage(A0, A1, B, ap, bp, (s + 1) * 32);
            __builtin_amdgcn_sched_barrier(0);   // loads may not sink past here
        }
        mfma_stage(fd, fp, fb, acc1, acc2);
    }

    // ---- store C partials: C/D layout col=lane&15, row=(lane>>4)*4+reg ----
    const long pbase = ((long)(b * nch + chunk)) * NP * MP;
    const int nr0 = (lane >> 4) * 4;
    #pragma unroll
    for (int mt = 0; mt < 4; mt++) {
        const int mloc = mt * 16 + r16;
        #pragma unroll
        for (int r = 0; r < 4; r++) {
            const int ng = ntile * 16 + nr0 + r;
            part1[pbase + ng * MP + mloc] = acc1[mt][r];
            part2[pbase + ng * MP + mloc] = acc2[mt][r];
        }
    }

    // ---- rsl row sums: lanes {r,r+16,r+32,r+48} hold row r's k-partials ----
    rsl += __shfl_xor(rsl, 16); rsl += __shfl_xor(rsl, 32);
    if (lane < 16)
        rspart[(long)(b * nch + chunk) * NP + ntile * 16 + lane] = rsl;
}

// 1-wave workgroups; each wave fully independent (no LDS, no barriers).
// waves_per_eu(4,4): VGPR budget 128 (fits the ~116-reg working set, no
// spill) AND forbids squeezing for >4 waves (rounds 2/3: squeeze to 60
// serialized loads; round 4: squeeze to 84 spilled). Grid supplies
// 3584 waves = 14/CU = 3.5/EU of genuine TLP.
__global__ __launch_bounds__(64)
__attribute__((amdgpu_waves_per_eu(4, 4)))
void matcher_main(const float* __restrict__ pred_masks,  // [4][100][65536]
                  const float* __restrict__ tgt_masks,   // [4][50][65536]
                  float* __restrict__ part1,             // [4][nch][112][64]
                  float* __restrict__ part2,             // [4][nch][112][64]
                  float* __restrict__ rspart,            // [4][nch][112]
                  int nch, int Kc)
{
    const int chunk = blockIdx.x;
    const int b     = blockIdx.y;
    const int ntile = blockIdx.z;        // 0..6
    if (ntile == 6)
        run_wave<true>(pred_masks, tgt_masks, part1, part2, rspart, nch, Kc, chunk, b, 6);
    else
        run_wave<false>(pred_masks, tgt_masks, part1, part2, rspart, nch, Kc, chunk, b, ntile);
}

// Epilogue: one block per (b,n), 1024 threads; 16-way chunk-group reduction.
// St comes from part1 row 100 (ones-row trick); Sp from part2 col 50
// (ones-col trick); rspart carries only rsl.
__global__ __launch_bounds__(1024)
void matcher_epilogue(const float* __restrict__ pred_logits, // [4][100][2]
                      const float* __restrict__ pred_style,  // [4][100][4]
                      const int*   __restrict__ styles,      // [4][50]
                      const float* __restrict__ part1,
                      const float* __restrict__ part2,
                      const float* __restrict__ rspart,
                      float* __restrict__ out, int nch)
{
    __shared__ float red1[16][64], red2[16][64], redt[16][64];
    __shared__ float slw[16];

    const int blk = blockIdx.x;          // 0..399
    const int b = blk / NQ, n = blk % NQ;
    const int t = threadIdx.x;
    const int m = t & 63, cg = t >> 6;   // cg in 0..15

    float S1 = 0.f, S2 = 0.f, St = 0.f;
    for (int c = cg; c < nch; c += 16) {
        const long cb = (long)(b * nch + c) * NP;
        S1 += part1[(cb + n) * MP + m];
        S2 += part2[(cb + n) * MP + m];
        St += part1[(cb + 100) * MP + m];   // ones-row: colsum(tm), exact
    }
    red1[cg][m] = S1; red2[cg][m] = S2; redt[cg][m] = St;

    // Sl across chunks: threads 0..nch-1 load, per-wave shuffle reduce
    float sl = 0.f;
    if (t < nch)
        sl = rspart[(long)(b * nch + t) * NP + n];
    #pragma unroll
    for (int off = 32; off; off >>= 1) sl += __shfl_down(sl, off);
    if ((t & 63) == 0) slw[t >> 6] = sl;
    __syncthreads();

    if (t < MQ) {
        float Sl = 0.f, Sp = 0.f, s1 = 0.f, s2 = 0.f, st = 0.f;
        #pragma unroll
        for (int w = 0; w < 16; w++) {
            Sl += slw[w];
            Sp += red2[w][50];              // ones-col: rowsum(pm)
            s1 += red1[w][t]; s2 += red2[w][t]; st += redt[w][t];
        }

        // classification: -softmax(logits)[1]
        const float l0 = pred_logits[(b * NQ + n) * 2 + 0];
        const float l1 = pred_logits[(b * NQ + n) * 2 + 1];
        const float p1 = 1.0f / (1.0f + __expf(l0 - l1));

        // style: -softmax(style)[sid]
        const float* stp = &pred_style[(b * NQ + n) * 4];
        const float v0 = stp[0], v1 = stp[1], v2 = stp[2], v3 = stp[3];
        const float mx = fmaxf(fmaxf(v0, v1), fmaxf(v2, v3));
        const float e0 = __expf(v0 - mx), e1 = __expf(v1 - mx),
                    e2 = __expf(v2 - mx), e3 = __expf(v3 - mx);
        const float esum = e0 + e1 + e2 + e3;
        int sid = styles[b * MQ + t];
        sid = min(max(sid, 0), 3);
        const float ps = (sid == 0 ? e0 : sid == 1 ? e1 : sid == 2 ? e2 : e3) / esum;

        const float cost_mask = -(s1 + Sl) * (1.0f / (float)HWSZ);
        const float dice = 1.0f - (2.0f * s2 + 1.0f) / (Sp + st + 1.0f);

        float c = 2.0f * (-p1) + 5.0f * cost_mask + 5.0f * dice + 1.0f * (-ps);
        if (isnan(c)) c = 10000.0f;
        else if (isinf(c)) c = (c > 0.f) ? 10000.0f : -10000.0f;
        out[(b * NQ + n) * MQ + t] = c;
    }
}

extern "C" void kernel_launch(void* const* d_in, const int* in_sizes, int n_in,
                              void* d_out, int out_size, void* d_ws, size_t ws_size,
                              hipStream_t stream) {
    const float* pred_logits = (const float*)d_in[0];
    const float* pred_masks  = (const float*)d_in[1];
    const float* pred_style  = (const float*)d_in[2];
    const float* tgt_masks   = (const float*)d_in[3];
    const int*   styles      = (const int*)d_in[4];
    float* out = (float*)d_out;

    // ws layout: part1/part2 [4][nch][112][64], rspart [4][nch][112]
    int nch = 8;
    for (int cand = 128; cand >= 8; cand >>= 1) {
        size_t need = (size_t)cand * (2ull * BQ * NP * MP * 4ull
                                      + (size_t)BQ * NP * 4ull);
        if (need <= ws_size) { nch = cand; break; }
    }
    const int Kc = HWSZ / nch;

    float* part1  = (float*)d_ws;
    float* part2  = part1 + (size_t)BQ * nch * NP * MP;
    float* rspart = part2 + (size_t)BQ * nch * NP * MP;

    dim3 grid(nch, BQ, 7);
    matcher_main<<<grid, 64, 0, stream>>>(pred_masks, tgt_masks, part1, part2, rspart, nch, Kc);

    matcher_epilogue<<<BQ * NQ, 1024, 0, stream>>>(
        pred_logits, pred_style, styles, part1, part2, rspart, out, nch);
}

// Round 7
// 228.230 us; speedup vs baseline: 1.2120x; 1.2120x over previous
//
#include <hip/hip_runtime.h>
#include <hip/hip_bf16.h>
#include <math.h>

// Problem constants
#define BQ 4
#define NQ 100
#define MQ 50
#define HWSZ 65536
#define NP 112   // padded N rows in partials (7 x 16)
#define MP 64    // padded M (4 x 16)
#define NCH 128  // K chunks (ws layout verified: every prior round selected 128)
#define KC 512   // HWSZ / NCH
#define NSTEPS 16 // KC / 32
#define DEPTH 3  // LDS pipeline depth (slabs in flight)
#define SLAB 9216  // bytes/step: A 16x32xf32 (2048) + B 56x32xf32 (7168)
#define BOFF 2048  // B region offset within slab
#define DCLAMP 13.8155106f   // logit(1-1e-6) = -logit(1e-6)
#define ONESBF2 0x3F803F80u  // two bf16 1.0s

typedef __attribute__((ext_vector_type(8))) short short8;
typedef __attribute__((ext_vector_type(4))) float f32x4;
typedef __attribute__((address_space(3))) char as3char;
typedef const __attribute__((address_space(1))) char as1char;

// d = log(pm)-log(1-pm) = clamp(x, +-13.8155) EXACTLY (logit o clip o sigmoid).
// pm = sigmoid(clamp(x)); l1m = log(1-pm) = -log(1+e^xc).
__device__ __forceinline__ void xform2(float x, float& d, float& pm, float& l1m) {
    float xc = fminf(fmaxf(x, -DCLAMP), DCLAMP);
    d = xc;
    float e = __expf(xc);                       // in [1e-6, 1e6], no overflow
    float r = __builtin_amdgcn_rcpf(1.0f + e);
    pm = e * r;
    l1m = -__logf(1.0f + e);
}

// pack two floats -> two bf16 (RTNE) in one u32
__device__ __forceinline__ unsigned pk2(float a, float b) {
    __hip_bfloat162 h = __float22bfloat162_rn(float2{a, b});
    unsigned u;
    __builtin_memcpy(&u, &h, 4);
    return u;
}

// build a bf16x8 MFMA fragment from two float4
__device__ __forceinline__ short8 mk8(float4 a, float4 b) {
    union { short8 s; unsigned u[4]; } r;
    r.u[0] = pk2(a.x, a.y); r.u[1] = pk2(a.z, a.w);
    r.u[2] = pk2(b.x, b.y); r.u[3] = pk2(b.z, b.w);
    return r.s;
}

// build a bf16x8 MFMA fragment from 8 scalars
__device__ __forceinline__ short8 mk8s(float a0, float a1, float a2, float a3,
                                       float a4, float a5, float a6, float a7) {
    union { short8 s; unsigned u[4]; } r;
    r.u[0] = pk2(a0, a1); r.u[1] = pk2(a2, a3);
    r.u[2] = pk2(a4, a5); r.u[3] = pk2(a6, a7);
    return r.s;
}

// LDS-pipelined, barrier-free main kernel (rounds 1-6 lesson: hipcc will not
// hold a register-resident prefetch pipeline -- it either squeezes VGPRs and
// serializes the loads (r2/r3/r5: 60-100 VGPR, 80-93us) or spills (r1/r4/r6:
// +75..95MB scratch). Fix: put the pipeline in LDS via global_load_lds,
// which consumes ZERO VGPRs and stays in flight across counted
// s_waitcnt vmcnt(N). Each wave stages its own private slabs -> vmcnt counts
// only its own loads -> no barriers, no cross-wave races.
//
// LDS swizzle (rule: swizzle both sides or neither): global_load_lds writes
// linearly (base + lane*16); a linear [row][128B] slab read per-fragment
// (rows at stride 128B, same col) is a 16-way bank conflict. So the 16B-chunk
// index is XOR'd with (row&7) on BOTH the staging SOURCE address (pre-swizzle,
// involution) and the ds_read address -> max 2-way (free).
template <bool ONES_ROW>
__device__ __forceinline__ void run_wave(
    const float* __restrict__ pred_masks, const float* __restrict__ tgt_masks,
    float* __restrict__ part1, float* __restrict__ part2,
    float* __restrict__ rspart,
    int chunk, int b, int ntile, char* lds)
{
    const int lane = threadIdx.x;        // 1-wave blocks
    const int r16  = lane & 15;
    const int kg   = lane >> 4;          // k-group 0..3 (8 floats each)
    const bool c50  = (r16 == 2);        // B col 48+2 = 50 (mt=3 ones-col)
    const bool rge4 = (r16 >= 4);        // A rows 100-111 (ntile=6 ones-rows)
    const int n0 = ntile * 16;

    // ---- staging source pointers, one per global_load_lds inst ----
    // inst j writes slab bytes [j*1024, j*1024+1024): lane -> +lane*16.
    // Source address carries the inverse (== same, involution) swizzle.
    const float* g[9];
    #pragma unroll
    for (int j = 0; j < 2; ++j) {        // A: slab rows 0..15 ([16][128B])
        const int o   = j * 1024 + lane * 16;
        const int row = o >> 7;
        const int c   = (o ^ ((row & 7) << 4)) & 127;   // swizzled byte col
        g[j] = pred_masks + (((long)(b * NQ + min(n0 + row, NQ - 1))) << 16)
             + chunk * KC + (c >> 2);
    }
    #pragma unroll
    for (int j = 0; j < 7; ++j) {        // B: slab rows 0..55 ([56][128B])
        const int o   = j * 1024 + lane * 16;
        const int row = o >> 7;
        const int c   = (o ^ ((row & 7) << 4)) & 127;
        g[j + 2] = tgt_masks + (((long)(b * MQ + min(row, MQ - 1))) << 16)
                 + chunk * KC + (c >> 2);
    }

    // ---- swizzled LDS read offsets (per-lane constants) ----
    // A fragment: row r16, k bytes kg*32 .. +31 (two float4 reads).
    const int oA   = r16 * 128 + kg * 32;
    const int aoff = oA ^ ((r16 & 7) << 4);
    int boff[4];
    #pragma unroll
    for (int mt = 0; mt < 4; ++mt) {
        const int rb = min(mt * 16 + r16, 55);   // rows 51..55 junk (unread cols)
        const int ob = rb * 128 + kg * 32;
        boff[mt] = BOFF + (ob ^ ((rb & 7) << 4));
    }

    f32x4 acc1[4], acc2[4];
    #pragma unroll
    for (int mt = 0; mt < 4; ++mt) {
        acc1[mt] = (f32x4){0.f, 0.f, 0.f, 0.f};
        acc2[mt] = (f32x4){0.f, 0.f, 0.f, 0.f};
    }
    float rsl = 0.f;

    // issue one step's 9 async global->LDS loads (no VGPR cost)
    auto stage = [&](int s) {
        char* dst = lds + (s % DEPTH) * SLAB;
        #pragma unroll
        for (int j = 0; j < 9; ++j) {
            __builtin_amdgcn_global_load_lds(
                (as1char*)(const char*)(g[j] + s * 32),
                (as3char*)(dst + j * 1024), 16, 0, 0);
        }
    };

    // consume one staged step: ds_read (swizzled), transform, pack, 8 MFMAs
    auto compute = [&](int s) {
        const char* sb = lds + (s % DEPTH) * SLAB;
        const float4 a0 = *(const float4*)(sb + aoff);
        const float4 a1 = *(const float4*)(sb + (aoff ^ 16));
        float4 bv0[4], bv1[4];
        #pragma unroll
        for (int mt = 0; mt < 4; ++mt) {
            bv0[mt] = *(const float4*)(sb + boff[mt]);
            bv1[mt] = *(const float4*)(sb + (boff[mt] ^ 16));
        }

        float d0,d1,d2,d3,d4,d5,d6,d7, p0,p1,p2,p3,p4,p5,p6,p7, l;
        xform2(a0.x, d0, p0, l); rsl += l;
        xform2(a0.y, d1, p1, l); rsl += l;
        xform2(a0.z, d2, p2, l); rsl += l;
        xform2(a0.w, d3, p3, l); rsl += l;
        xform2(a1.x, d4, p4, l); rsl += l;
        xform2(a1.y, d5, p5, l); rsl += l;
        xform2(a1.z, d6, p6, l); rsl += l;
        xform2(a1.w, d7, p7, l); rsl += l;
        short8 fd = mk8s(d0,d1,d2,d3,d4,d5,d6,d7);
        const short8 fp = mk8s(p0,p1,p2,p3,p4,p5,p6,p7);

        if (ONES_ROW) {  // acc1 rows 100-111 -> colsum(tm) = St (exact)
            union { short8 s8; unsigned u[4]; } f; f.s8 = fd;
            f.u[0] = rge4 ? ONESBF2 : f.u[0];
            f.u[1] = rge4 ? ONESBF2 : f.u[1];
            f.u[2] = rge4 ? ONESBF2 : f.u[2];
            f.u[3] = rge4 ? ONESBF2 : f.u[3];
            fd = f.s8;
        }

        #pragma unroll
        for (int mt = 0; mt < 4; ++mt) {
            union { short8 s8; unsigned u[4]; } f;
            f.s8 = mk8(bv0[mt], bv1[mt]);
            if (mt == 3) {  // acc2 col 50 -> rowsum(pm) = Sp
                f.u[0] = c50 ? ONESBF2 : f.u[0];
                f.u[1] = c50 ? ONESBF2 : f.u[1];
                f.u[2] = c50 ? ONESBF2 : f.u[2];
                f.u[3] = c50 ? ONESBF2 : f.u[3];
            }
            acc1[mt] = __builtin_amdgcn_mfma_f32_16x16x32_bf16(fd, f.s8, acc1[mt], 0, 0, 0);
            acc2[mt] = __builtin_amdgcn_mfma_f32_16x16x32_bf16(fp, f.s8, acc2[mt], 0, 0, 0);
        }
    };

    // prologue: fill the 3-deep ring (27 loads in flight, vmcnt max 63 ok)
    stage(0); stage(1); stage(2);

    // steady state: wait until step s's 9 loads done (2 steps / 18 loads stay
    // in flight), consume, then refill the just-freed buffer for step s+3.
    // The refill is issued only AFTER compute(s) consumed every ds_read value
    // (compiler waits lgkmcnt before use), so no LDS write/read race.
    for (int s = 0; s < 14; ++s) {
        asm volatile("s_waitcnt vmcnt(18)" ::: "memory");
        compute(s);
        if (s < 13) stage(s + 3);
    }
    asm volatile("s_waitcnt vmcnt(9)" ::: "memory");
    compute(14);
    asm volatile("s_waitcnt vmcnt(0)" ::: "memory");
    compute(15);

    // ---- store C partials: C/D layout col=lane&15, row=(lane>>4)*4+reg ----
    const long pbase = ((long)(b * NCH + chunk)) * NP * MP;
    const int nr0 = kg * 4;
    #pragma unroll
    for (int mt = 0; mt < 4; ++mt) {
        const int mloc = mt * 16 + r16;
        #pragma unroll
        for (int r = 0; r < 4; ++r) {
            const int ng = n0 + nr0 + r;
            part1[pbase + ng * MP + mloc] = acc1[mt][r];
            part2[pbase + ng * MP + mloc] = acc2[mt][r];
        }
    }

    // ---- rsl row sums: lanes {r,r+16,r+32,r+48} hold row r's k-partials ----
    rsl += __shfl_xor(rsl, 16); rsl += __shfl_xor(rsl, 32);
    if (lane < 16)
        rspart[(long)(b * NCH + chunk) * NP + n0 + lane] = rsl;
}

// 1-wave workgroups, 27.6 KB LDS each -> 5 blocks/CU (LDS-capped).
// launch_bounds(64, 1): min-1-wave/EU tells the allocator it may use the
// full 256-VGPR budget -- no squeeze (r2/r3/r5 failure), and the working
// set (~110 regs, loads target LDS not VGPRs) can't spill (r1/r4/r6 failure).
__global__ __launch_bounds__(64, 1)
void matcher_main(const float* __restrict__ pred_masks,  // [4][100][65536]
                  const float* __restrict__ tgt_masks,   // [4][50][65536]
                  float* __restrict__ part1,             // [4][128][112][64]
                  float* __restrict__ part2,             // [4][128][112][64]
                  float* __restrict__ rspart)            // [4][128][112]
{
    __shared__ __align__(16) char lds[DEPTH * SLAB];
    const int chunk = blockIdx.x;
    const int b     = blockIdx.y;
    const int ntile = blockIdx.z;        // 0..6
    if (ntile == 6)
        run_wave<true>(pred_masks, tgt_masks, part1, part2, rspart, chunk, b, 6, lds);
    else
        run_wave<false>(pred_masks, tgt_masks, part1, part2, rspart, chunk, b, ntile, lds);
}

// Epilogue: one block per (b,n), 1024 threads; 16-way chunk-group reduction.
// St comes from part1 row 100 (ones-row trick); Sp from part2 col 50
// (ones-col trick); rspart carries only rsl.
__global__ __launch_bounds__(1024)
void matcher_epilogue(const float* __restrict__ pred_logits, // [4][100][2]
                      const float* __restrict__ pred_style,  // [4][100][4]
                      const int*   __restrict__ styles,      // [4][50]
                      const float* __restrict__ part1,
                      const float* __restrict__ part2,
                      const float* __restrict__ rspart,
                      float* __restrict__ out, int nch)
{
    __shared__ float red1[16][64], red2[16][64], redt[16][64];
    __shared__ float slw[16];

    const int blk = blockIdx.x;          // 0..399
    const int b = blk / NQ, n = blk % NQ;
    const int t = threadIdx.x;
    const int m = t & 63, cg = t >> 6;   // cg in 0..15

    float S1 = 0.f, S2 = 0.f, St = 0.f;
    for (int c = cg; c < nch; c += 16) {
        const long cb = (long)(b * nch + c) * NP;
        S1 += part1[(cb + n) * MP + m];
        S2 += part2[(cb + n) * MP + m];
        St += part1[(cb + 100) * MP + m];   // ones-row: colsum(tm), exact
    }
    red1[cg][m] = S1; red2[cg][m] = S2; redt[cg][m] = St;

    // Sl across chunks: threads 0..nch-1 load, per-wave shuffle reduce
    float sl = 0.f;
    if (t < nch)
        sl = rspart[(long)(b * nch + t) * NP + n];
    #pragma unroll
    for (int off = 32; off; off >>= 1) sl += __shfl_down(sl, off);
    if ((t & 63) == 0) slw[t >> 6] = sl;
    __syncthreads();

    if (t < MQ) {
        float Sl = 0.f, Sp = 0.f, s1 = 0.f, s2 = 0.f, st = 0.f;
        #pragma unroll
        for (int w = 0; w < 16; w++) {
            Sl += slw[w];
            Sp += red2[w][50];              // ones-col: rowsum(pm)
            s1 += red1[w][t]; s2 += red2[w][t]; st += redt[w][t];
        }

        // classification: -softmax(logits)[1]
        const float l0 = pred_logits[(b * NQ + n) * 2 + 0];
        const float l1 = pred_logits[(b * NQ + n) * 2 + 1];
        const float p1 = 1.0f / (1.0f + __expf(l0 - l1));

        // style: -softmax(style)[sid]
        const float* stp = &pred_style[(b * NQ + n) * 4];
        const float v0 = stp[0], v1 = stp[1], v2 = stp[2], v3 = stp[3];
        const float mx = fmaxf(fmaxf(v0, v1), fmaxf(v2, v3));
        const float e0 = __expf(v0 - mx), e1 = __expf(v1 - mx),
                    e2 = __expf(v2 - mx), e3 = __expf(v3 - mx);
        const float esum = e0 + e1 + e2 + e3;
        int sid = styles[b * MQ + t];
        sid = min(max(sid, 0), 3);
        const float ps = (sid == 0 ? e0 : sid == 1 ? e1 : sid == 2 ? e2 : e3) / esum;

        const float cost_mask = -(s1 + Sl) * (1.0f / (float)HWSZ);
        const float dice = 1.0f - (2.0f * s2 + 1.0f) / (Sp + st + 1.0f);

        float c = 2.0f * (-p1) + 5.0f * cost_mask + 5.0f * dice + 1.0f * (-ps);
        if (isnan(c)) c = 10000.0f;
        else if (isinf(c)) c = (c > 0.f) ? 10000.0f : -10000.0f;
        out[(b * NQ + n) * MQ + t] = c;
    }
}

extern "C" void kernel_launch(void* const* d_in, const int* in_sizes, int n_in,
                              void* d_out, int out_size, void* d_ws, size_t ws_size,
                              hipStream_t stream) {
    const float* pred_logits = (const float*)d_in[0];
    const float* pred_masks  = (const float*)d_in[1];
    const float* pred_style  = (const float*)d_in[2];
    const float* tgt_masks   = (const float*)d_in[3];
    const int*   styles      = (const int*)d_in[4];
    float* out = (float*)d_out;

    // ws layout: part1/part2 [4][128][112][64], rspart [4][128][112]
    // (29.6 MB; every prior round's ws_size accommodated nch=128)
    float* part1  = (float*)d_ws;
    float* part2  = part1 + (size_t)BQ * NCH * NP * MP;
    float* rspart = part2 + (size_t)BQ * NCH * NP * MP;

    dim3 grid(NCH, BQ, 7);
    matcher_main<<<grid, 64, 0, stream>>>(pred_masks, tgt_masks, part1, part2, rspart);

    matcher_epilogue<<<BQ * NQ, 1024, 0, stream>>>(
        pred_logits, pred_style, styles, part1, part2, rspart, out, NCH);
}

// Round 8
// 215.624 us; speedup vs baseline: 1.2828x; 1.0585x over previous
//
#include <hip/hip_runtime.h>
#include <hip/hip_bf16.h>
#include <math.h>

// Problem constants
#define BQ 4
#define NQ 100
#define MQ 50
#define HWSZ 65536
#define NP 112    // padded N rows in partials (7 x 16)
#define MP 64     // padded M (4 x 16)
#define NCH 128   // K chunks
#define KC 512    // HWSZ / NCH
#define NSTEPS 16 // KC / 32
#define DEPTH 3   // LDS ring depth
#define ABYTES 14336  // A slab: 112 rows x 128 B (one 32-float k-step)
#define BBYTES 7168   // B slab:  56 rows x 128 B
#define SLAB (ABYTES + BBYTES)   // 21504 B; x3 = 64512 B (< 64 KB static)
#define DCLAMP 13.8155106f   // logit(1-1e-6) = -logit(1e-6)
#define ONESBF2 0x3F803F80u  // two bf16 1.0s

typedef __attribute__((ext_vector_type(8))) short short8;
typedef __attribute__((ext_vector_type(4))) float f32x4;
typedef __attribute__((address_space(3))) char as3char;
typedef const __attribute__((address_space(1))) char as1char;

// d = log(pm)-log(1-pm) = clamp(x, +-13.8155) EXACTLY (logit o clip o sigmoid).
// pm = sigmoid(clamp(x)); l1m = log(1-pm) = -log(1+e^xc).
__device__ __forceinline__ void xform2(float x, float& d, float& pm, float& l1m) {
    float xc = fminf(fmaxf(x, -DCLAMP), DCLAMP);
    d = xc;
    float e = __expf(xc);                       // in [1e-6, 1e6], no overflow
    float r = __builtin_amdgcn_rcpf(1.0f + e);
    pm = e * r;
    l1m = -__logf(1.0f + e);
}

// pack two floats -> two bf16 (RTNE) in one u32
__device__ __forceinline__ unsigned pk2(float a, float b) {
    __hip_bfloat162 h = __float22bfloat162_rn(float2{a, b});
    unsigned u;
    __builtin_memcpy(&u, &h, 4);
    return u;
}

// build a bf16x8 MFMA fragment from two float4
__device__ __forceinline__ short8 mk8(float4 a, float4 b) {
    union { short8 s; unsigned u[4]; } r;
    r.u[0] = pk2(a.x, a.y); r.u[1] = pk2(a.z, a.w);
    r.u[2] = pk2(b.x, b.y); r.u[3] = pk2(b.z, b.w);
    return r.s;
}

// build a bf16x8 MFMA fragment from 8 scalars
__device__ __forceinline__ short8 mk8s(float a0, float a1, float a2, float a3,
                                       float a4, float a5, float a6, float a7) {
    union { short8 s; unsigned u[4]; } r;
    r.u[0] = pk2(a0, a1); r.u[1] = pk2(a2, a3);
    r.u[2] = pk2(a4, a5); r.u[3] = pk2(a6, a7);
    return r.s;
}

// B-SHARED main kernel. Rounds 2-7 all pinned at 80-93us independent of
// occupancy (11%..36%) and structure: the binding limit was REQUESTED bytes
// through the per-CU vector path (A once + B x7 redundant = 472 MB =
// 8.8 B/cy/CU = 86% of the ~10.2 B/cy/CU global-load ceiling, m13). This
// version stages B ONCE per (chunk,b) block, shared by 7 n-tile waves via
// LDS: requested bytes drop to 157 MB (2.5x).
//
// Machinery kept from r7 (the parts that worked): all global traffic via
// global_load_lds (zero VGPR -> allocator can't squeeze or spill it, the
// r1-r6 graveyard), counted vmcnt (never 0 in-loop), 3-deep LDS ring,
// both-sides XOR swizzle. New: 7-wave cooperative staging with ONE
// s_barrier per K-step: each wave waits vmcnt(3) for its OWN 3 stage
// insts, then barrier => slab complete collectively (m201 pattern);
// stage(s+2) after the barrier overwrites buf[(s-1)%3] whose readers all
// passed that barrier -> race-free.
__global__ __launch_bounds__(448)
void matcher_main(const float* __restrict__ pred_masks,  // [4][100][65536]
                  const float* __restrict__ tgt_masks,   // [4][50][65536]
                  float* __restrict__ part1,             // [4][128][112][64]
                  float* __restrict__ part2,             // [4][128][112][64]
                  float* __restrict__ rspart)            // [4][128][112]
{
    __shared__ __align__(16) char lds[DEPTH * SLAB];   // 64512 B -> 2 blocks/CU
    const int t    = threadIdx.x;
    const int lane = t & 63;
    const int wv   = t >> 6;          // wave = n-tile 0..6
    const int r16  = lane & 15;
    const int kg   = lane >> 4;       // k-group 0..3 (8 floats)
    const int chunk = blockIdx.x;
    const int b     = blockIdx.y;
    const int n0    = wv * 16;
    const bool c50     = (r16 == 2);               // B col 50 ones-col (Sp)
    const bool onesrow = (wv == 6) && (r16 >= 4);  // A rows 100-111 ones (St)

    // ---- staging sources: 3 global_load_lds per thread per step ----
    // LDS layout is swizzled: LDS[row*128 + (col ^ ((row&7)<<4))] = G[row][col].
    // global_load_lds writes linearly (base + lane*16), so the SOURCE carries
    // the (involutive) swizzle; dest bases are wave-uniform.
    const float *gsA0, *gsA1, *gsB;
    {
        const int o0 = (wv * 2 + 0) * 1024 + lane * 16;   // A slab byte
        const int r0 = o0 >> 7;                           // A row 0..111
        gsA0 = pred_masks + (((long)(b * NQ + min(r0, NQ - 1))) << 16)
             + chunk * KC + ((((o0 ^ ((r0 & 7) << 4))) & 127) >> 2);
        const int o1 = (wv * 2 + 1) * 1024 + lane * 16;
        const int r1 = o1 >> 7;
        gsA1 = pred_masks + (((long)(b * NQ + min(r1, NQ - 1))) << 16)
             + chunk * KC + ((((o1 ^ ((r1 & 7) << 4))) & 127) >> 2);
        const int ob = wv * 1024 + lane * 16;             // B slab byte
        const int rb = ob >> 7;                           // B row 0..55
        gsB = tgt_masks + (((long)(b * MQ + min(rb, MQ - 1))) << 16)
            + chunk * KC + ((((ob ^ ((rb & 7) << 4))) & 127) >> 2);
    }
    const int dA0 = (wv * 2 + 0) * 1024;   // wave-uniform LDS dest bases
    const int dA1 = (wv * 2 + 1) * 1024;
    const int dB  = ABYTES + wv * 1024;

    // ---- swizzled ds_read offsets ----
    const int ar   = n0 + r16;                              // A row (0..111)
    const int aoff = (ar * 128 + kg * 32) ^ ((r16 & 7) << 4);
    int boff[4];
    #pragma unroll
    for (int mt = 0; mt < 4; ++mt) {
        const int rb = min(mt * 16 + r16, 55);  // rows 51..55 junk (unread cols)
        boff[mt] = ABYTES + ((rb * 128 + kg * 32) ^ ((rb & 7) << 4));
    }

    f32x4 acc1[4], acc2[4];
    #pragma unroll
    for (int mt = 0; mt < 4; ++mt) {
        acc1[mt] = (f32x4){0.f, 0.f, 0.f, 0.f};
        acc2[mt] = (f32x4){0.f, 0.f, 0.f, 0.f};
    }
    float rsl = 0.f;

    // issue this thread's 3 async global->LDS loads for step s (no VGPR cost)
    auto stage = [&](int s) {
        char* dst = lds + (s % DEPTH) * SLAB;
        __builtin_amdgcn_global_load_lds((as1char*)(const char*)(gsA0 + s * 32),
                                         (as3char*)(dst + dA0), 16, 0, 0);
        __builtin_amdgcn_global_load_lds((as1char*)(const char*)(gsA1 + s * 32),
                                         (as3char*)(dst + dA1), 16, 0, 0);
        __builtin_amdgcn_global_load_lds((as1char*)(const char*)(gsB + s * 32),
                                         (as3char*)(dst + dB), 16, 0, 0);
    };

    // consume one staged step: ds_read (swizzled), transform, pack, 8 MFMAs
    auto compute = [&](int s) {
        const char* sb = lds + (s % DEPTH) * SLAB;
        const float4 a0 = *(const float4*)(sb + aoff);
        const float4 a1 = *(const float4*)(sb + (aoff ^ 16));
        float4 bv0[4], bv1[4];
        #pragma unroll
        for (int mt = 0; mt < 4; ++mt) {
            bv0[mt] = *(const float4*)(sb + boff[mt]);
            bv1[mt] = *(const float4*)(sb + (boff[mt] ^ 16));
        }

        float d0,d1,d2,d3,d4,d5,d6,d7, p0,p1,p2,p3,p4,p5,p6,p7, l;
        xform2(a0.x, d0, p0, l); rsl += l;
        xform2(a0.y, d1, p1, l); rsl += l;
        xform2(a0.z, d2, p2, l); rsl += l;
        xform2(a0.w, d3, p3, l); rsl += l;
        xform2(a1.x, d4, p4, l); rsl += l;
        xform2(a1.y, d5, p5, l); rsl += l;
        xform2(a1.z, d6, p6, l); rsl += l;
        xform2(a1.w, d7, p7, l); rsl += l;
        short8 fd = mk8s(d0,d1,d2,d3,d4,d5,d6,d7);
        const short8 fp = mk8s(p0,p1,p2,p3,p4,p5,p6,p7);

        {   // acc1 rows 100-111 -> colsum(tm) = St (exact; wave 6 only)
            union { short8 s8; unsigned u[4]; } f; f.s8 = fd;
            f.u[0] = onesrow ? ONESBF2 : f.u[0];
            f.u[1] = onesrow ? ONESBF2 : f.u[1];
            f.u[2] = onesrow ? ONESBF2 : f.u[2];
            f.u[3] = onesrow ? ONESBF2 : f.u[3];
            fd = f.s8;
        }

        #pragma unroll
        for (int mt = 0; mt < 4; ++mt) {
            union { short8 s8; unsigned u[4]; } f;
            f.s8 = mk8(bv0[mt], bv1[mt]);
            if (mt == 3) {  // acc2 col 50 -> rowsum(pm) = Sp
                f.u[0] = c50 ? ONESBF2 : f.u[0];
                f.u[1] = c50 ? ONESBF2 : f.u[1];
                f.u[2] = c50 ? ONESBF2 : f.u[2];
                f.u[3] = c50 ? ONESBF2 : f.u[3];
            }
            acc1[mt] = __builtin_amdgcn_mfma_f32_16x16x32_bf16(fd, f.s8, acc1[mt], 0, 0, 0);
            acc2[mt] = __builtin_amdgcn_mfma_f32_16x16x32_bf16(fp, f.s8, acc2[mt], 0, 0, 0);
        }
    };

    // prologue: 2 slabs in flight (6 insts/thread outstanding)
    stage(0); stage(1);

    for (int s = 0; s < NSTEPS; ++s) {
        // own slab-s insts are the oldest; leave slab s+1's 3 in flight.
        if (s < NSTEPS - 1) asm volatile("s_waitcnt vmcnt(3)" ::: "memory");
        else                asm volatile("s_waitcnt vmcnt(0)" ::: "memory");
        // all waves: slab s complete; all waves finished compute(s-1).
        asm volatile("s_barrier" ::: "memory");
        // overwrite buf[(s+2)%3] == buf[(s-1)%3]: safe after the barrier.
        if (s + 2 < NSTEPS) stage(s + 2);
        compute(s);
    }

    // ---- store C partials: C/D layout col=lane&15, row=(lane>>4)*4+reg ----
    const long pbase = ((long)(b * NCH + chunk)) * NP * MP;
    const int nr0 = kg * 4;
    #pragma unroll
    for (int mt = 0; mt < 4; ++mt) {
        const int mloc = mt * 16 + r16;
        #pragma unroll
        for (int r = 0; r < 4; ++r) {
            const int ng = n0 + nr0 + r;
            part1[pbase + ng * MP + mloc] = acc1[mt][r];
            part2[pbase + ng * MP + mloc] = acc2[mt][r];
        }
    }

    // ---- rsl row sums: lanes {r,r+16,r+32,r+48} hold row r's k-partials ----
    rsl += __shfl_xor(rsl, 16); rsl += __shfl_xor(rsl, 32);
    if (lane < 16)
        rspart[(long)(b * NCH + chunk) * NP + n0 + lane] = rsl;
}

// Epilogue: one block per (b,n), 1024 threads; 16-way chunk-group reduction.
// St comes from part1 row 100 (ones-row trick); Sp from part2 col 50
// (ones-col trick); rspart carries only rsl.
__global__ __launch_bounds__(1024)
void matcher_epilogue(const float* __restrict__ pred_logits, // [4][100][2]
                      const float* __restrict__ pred_style,  // [4][100][4]
                      const int*   __restrict__ styles,      // [4][50]
                      const float* __restrict__ part1,
                      const float* __restrict__ part2,
                      const float* __restrict__ rspart,
                      float* __restrict__ out, int nch)
{
    __shared__ float red1[16][64], red2[16][64], redt[16][64];
    __shared__ float slw[16];

    const int blk = blockIdx.x;          // 0..399
    const int b = blk / NQ, n = blk % NQ;
    const int t = threadIdx.x;
    const int m = t & 63, cg = t >> 6;   // cg in 0..15

    float S1 = 0.f, S2 = 0.f, St = 0.f;
    for (int c = cg; c < nch; c += 16) {
        const long cb = (long)(b * nch + c) * NP;
        S1 += part1[(cb + n) * MP + m];
        S2 += part2[(cb + n) * MP + m];
        St += part1[(cb + 100) * MP + m];   // ones-row: colsum(tm), exact
    }
    red1[cg][m] = S1; red2[cg][m] = S2; redt[cg][m] = St;

    // Sl across chunks: threads 0..nch-1 load, per-wave shuffle reduce
    float sl = 0.f;
    if (t < nch)
        sl = rspart[(long)(b * nch + t) * NP + n];
    #pragma unroll
    for (int off = 32; off; off >>= 1) sl += __shfl_down(sl, off);
    if ((t & 63) == 0) slw[t >> 6] = sl;
    __syncthreads();

    if (t < MQ) {
        float Sl = 0.f, Sp = 0.f, s1 = 0.f, s2 = 0.f, st = 0.f;
        #pragma unroll
        for (int w = 0; w < 16; w++) {
            Sl += slw[w];
            Sp += red2[w][50];              // ones-col: rowsum(pm)
            s1 += red1[w][t]; s2 += red2[w][t]; st += redt[w][t];
        }

        // classification: -softmax(logits)[1]
        const float l0 = pred_logits[(b * NQ + n) * 2 + 0];
        const float l1 = pred_logits[(b * NQ + n) * 2 + 1];
        const float p1 = 1.0f / (1.0f + __expf(l0 - l1));

        // style: -softmax(style)[sid]
        const float* stp = &pred_style[(b * NQ + n) * 4];
        const float v0 = stp[0], v1 = stp[1], v2 = stp[2], v3 = stp[3];
        const float mx = fmaxf(fmaxf(v0, v1), fmaxf(v2, v3));
        const float e0 = __expf(v0 - mx), e1 = __expf(v1 - mx),
                    e2 = __expf(v2 - mx), e3 = __expf(v3 - mx);
        const float esum = e0 + e1 + e2 + e3;
        int sid = styles[b * MQ + t];
        sid = min(max(sid, 0), 3);
        const float ps = (sid == 0 ? e0 : sid == 1 ? e1 : sid == 2 ? e2 : e3) / esum;

        const float cost_mask = -(s1 + Sl) * (1.0f / (float)HWSZ);
        const float dice = 1.0f - (2.0f * s2 + 1.0f) / (Sp + st + 1.0f);

        float c = 2.0f * (-p1) + 5.0f * cost_mask + 5.0f * dice + 1.0f * (-ps);
        if (isnan(c)) c = 10000.0f;
        else if (isinf(c)) c = (c > 0.f) ? 10000.0f : -10000.0f;
        out[(b * NQ + n) * MQ + t] = c;
    }
}

extern "C" void kernel_launch(void* const* d_in, const int* in_sizes, int n_in,
                              void* d_out, int out_size, void* d_ws, size_t ws_size,
                              hipStream_t stream) {
    const float* pred_logits = (const float*)d_in[0];
    const float* pred_masks  = (const float*)d_in[1];
    const float* pred_style  = (const float*)d_in[2];
    const float* tgt_masks   = (const float*)d_in[3];
    const int*   styles      = (const int*)d_in[4];
    float* out = (float*)d_out;

    // ws layout: part1/part2 [4][128][112][64], rspart [4][128][112] (29.6 MB)
    float* part1  = (float*)d_ws;
    float* part2  = part1 + (size_t)BQ * NCH * NP * MP;
    float* rspart = part2 + (size_t)BQ * NCH * NP * MP;

    dim3 grid(NCH, BQ);    // 512 blocks x 448 thr = 2 blocks/CU, one full round
    matcher_main<<<grid, 448, 0, stream>>>(pred_masks, tgt_masks, part1, part2, rspart);

    matcher_epilogue<<<BQ * NQ, 1024, 0, stream>>>(
        pred_logits, pred_style, styles, part1, part2, rspart, out, NCH);
}